// Round 4
// baseline (35912.695 us; speedup 1.0000x reference)
//
#include <hip/hip_runtime.h>
#include <hip/hip_bf16.h>
#include <math.h>

#define N_NODES 50000
#define E1 300000
#define EN 30000
#define ETOT 330000

typedef __hip_bfloat16 bf16;

__device__ __forceinline__ float b2f(bf16 x){ return __bfloat162float(x); }
__device__ __forceinline__ bf16 f2b(float x){ return __float2bfloat16(x); }

// dual-dtype load/store: f32==true -> buffer is float32, else bf16
__device__ __forceinline__ float ldf(const void* p, long i, bool f32){
  return f32 ? ((const float*)p)[i] : b2f(((const bf16*)p)[i]);
}
__device__ __forceinline__ void stf(void* p, long i, float v, bool f32){
  if (f32) ((float*)p)[i] = v; else ((bf16*)p)[i] = f2b(v);
}

template<int NT>
__device__ __forceinline__ float block_sum(float v){
  __shared__ float sm[NT/64];
  #pragma unroll
  for (int o=32;o>0;o>>=1) v += __shfl_down(v,o);
  if ((threadIdx.x & 63)==0) sm[threadIdx.x>>6] = v;
  __syncthreads();
  float t = 0.f;
  #pragma unroll
  for (int w=0;w<NT/64;w++) t += sm[w];
  __syncthreads();
  return t;
}

// Detect input dtype: bf16 stream -> ~all uint16 exponent fields sane; fp32 -> ~56%.
__global__ void k_detect(const void* __restrict__ emb, int* __restrict__ flag){
  const unsigned short* h = (const unsigned short*)emb;
  int sane = 0;
  for (int i=0;i<128;i++){
    unsigned e = (h[i]>>7)&0xFFu;
    if (e>=112u && e<=143u) sane++;
  }
  *flag = (sane >= 112) ? 0 : 1;   // 1 => float32 inputs/outputs
}

// Layer-1 node projections (l2norm fused): pd/ps fp32, score scalars sd/ss
__global__ void k_proj1(const void* __restrict__ emb, const void* __restrict__ a,
                        const void* __restrict__ a2, const int* __restrict__ flag,
                        float* __restrict__ pd, float* __restrict__ ps,
                        float* __restrict__ sd, float* __restrict__ ss){
  bool f32 = flag[0] != 0;
  int n = blockIdx.x, j = threadIdx.x;   // 128 threads
  __shared__ float xs[128];
  float v = ldf(emb, (long)n*128 + j, f32);
  float nrm = fmaxf(sqrtf(block_sum<128>(v*v)), 1e-12f);
  xs[j] = v / nrm;
  __syncthreads();
  long ar = (long)j*384;
  float ad = 0.f, asv = 0.f;
  #pragma unroll 4
  for (int k=0;k<128;k++){
    float xk = xs[k];
    ad  += xk*ldf(a, ar+k, f32);
    asv += xk*ldf(a, ar+128+k, f32);
  }
  pd[(long)n*128+j] = ad; ps[(long)n*128+j] = asv;
  float a2j = ldf(a2, j, f32);
  float sdv = block_sum<128>(ad*a2j);
  float ssv = block_sum<128>(asv*a2j);
  if (j==0){ sd[n] = sdv; ss[n] = ssv; }
}

// Layer-1 relation projection: rp[t] fp32, sr[t]
__global__ void k_rproj1(const void* __restrict__ rel, const void* __restrict__ a,
                         const void* __restrict__ a2, const int* __restrict__ flag,
                         float* __restrict__ rp, float* __restrict__ sr){
  bool f32 = flag[0] != 0;
  int t = blockIdx.x, j = threadIdx.x;   // 128 threads
  __shared__ float rs_[128];
  rs_[j] = ldf(rel, (long)t*128 + j, f32);
  __syncthreads();
  long ar = (long)j*384 + 256;
  float acc = 0.f;
  #pragma unroll 4
  for (int k=0;k<128;k++) acc += rs_[k]*ldf(a, ar+k, f32);
  rp[(long)t*128+j] = acc;
  float v = block_sum<128>(acc*ldf(a2, j, f32));
  if (j==0) sr[t] = v;
}

// Edge scatter: one wave/edge. w=exp(-lrelu(score)); scat[dst] += w*(ps[src]+rp[type])
template<int D>
__global__ void k_edge(const int* __restrict__ el, const int* __restrict__ et,
                       const int* __restrict__ eln, const int* __restrict__ etn,
                       const float* __restrict__ ps, const float* __restrict__ rp,
                       const float* __restrict__ sd, const float* __restrict__ ss,
                       const float* __restrict__ sr,
                       float* __restrict__ scat, float* __restrict__ rowsum){
  long gid = (long)blockIdx.x*blockDim.x + threadIdx.x;
  long wid = gid >> 6;
  int lane = threadIdx.x & 63;
  if (wid >= ETOT) return;
  int dst, src; const float *pr1, *pr2 = nullptr; float srv;
  if (wid < E1){
    int e = (int)wid;
    dst = el[e]; src = el[E1 + e];
    int t = et[e]; pr1 = rp + (long)t*D; srv = sr[t];
  } else {
    int e = (int)wid - E1;
    dst = eln[e]; src = eln[EN + e];
    int t0 = etn[2*e], t1 = etn[2*e+1];
    pr1 = rp + (long)t0*D; pr2 = rp + (long)t1*D; srv = sr[t0] + sr[t1];
  }
  float score = sd[dst] + ss[src] + srv;
  float lr = score > 0.f ? score : 0.2f*score;
  float w = expf(-lr);
  if (lane == 0) atomicAdd(rowsum + dst, w);
  const float* psr = ps + (long)src*D;
  float* outp = scat + (long)dst*D;
  if (pr2){
    #pragma unroll
    for (int j=lane; j<D; j+=64) atomicAdd(outp+j, w*(psr[j] + pr1[j] + pr2[j]));
  } else {
    #pragma unroll
    for (int j=lane; j<D; j+=64) atomicAdd(outp+j, w*(psr[j] + pr1[j]));
  }
}

// Layer-1 finalize: x[:, hoff+j] = elu((rs*pd + scat)/denom), fp32
__global__ void k_fin1(const float* __restrict__ pd, const float* __restrict__ scat,
                       const float* __restrict__ rowsum, float* __restrict__ x, int hoff){
  int n = blockIdx.x, j = threadIdx.x;   // 128 threads
  float rs = rowsum[n];
  float denom = (rs == 0.f) ? 1e-12f : rs;
  float hr = rs*pd[(long)n*128+j] + scat[(long)n*128+j];
  float hv = hr/denom;
  hv = hv > 0.f ? hv : (expf(hv) - 1.f);
  x[(long)n*256 + hoff + j] = hv;
}

// out_relation_1 = rel @ W  (fp32 copy to ws + dual-dtype output at element offset)
__global__ void k_rel2(const void* __restrict__ rel, const void* __restrict__ W,
                       const int* __restrict__ flag,
                       float* __restrict__ r2, void* __restrict__ out){
  bool f32 = flag[0] != 0;
  int t = blockIdx.x, j = threadIdx.x;   // 256 threads
  __shared__ float rs_[128];
  if (j < 128) rs_[j] = ldf(rel, (long)t*128 + j, f32);
  __syncthreads();
  float acc = 0.f;
  #pragma unroll 4
  for (int k=0;k<128;k++) acc += rs_[k]*ldf(W, (long)k*256 + j, f32);
  r2[(long)t*256+j] = acc;
  stf(out, 12800000L + (long)t*256 + j, acc, f32);
}

// Layer-2 relation projection: rp2 fp32, sr2
__global__ void k_rproj2(const float* __restrict__ r2, const void* __restrict__ a,
                         const void* __restrict__ a2, const int* __restrict__ flag,
                         float* __restrict__ rp, float* __restrict__ sr){
  bool f32 = flag[0] != 0;
  int t = blockIdx.x, j = threadIdx.x;   // 256 threads
  __shared__ float rs_[256];
  rs_[j] = r2[(long)t*256 + j];
  __syncthreads();
  long ar = (long)j*768 + 512;
  float acc = 0.f;
  #pragma unroll 4
  for (int k=0;k<256;k++) acc += rs_[k]*ldf(a, ar+k, f32);
  rp[(long)t*256+j] = acc;
  float v = block_sum<256>(acc*ldf(a2, j, f32));
  if (j==0) sr[t] = v;
}

// Layer-2 node projections: p2d/p2s fp32, score scalars
__global__ void k_proj2(const float* __restrict__ x, const void* __restrict__ a,
                        const void* __restrict__ a2, const int* __restrict__ flag,
                        float* __restrict__ p2d, float* __restrict__ p2s,
                        float* __restrict__ s2d, float* __restrict__ s2s){
  bool f32 = flag[0] != 0;
  int n = blockIdx.x, j = threadIdx.x;   // 256 threads
  __shared__ float xs[256];
  xs[j] = x[(long)n*256 + j];
  __syncthreads();
  long ar = (long)j*768;
  float ad = 0.f, asv = 0.f;
  #pragma unroll 4
  for (int k=0;k<256;k++){
    float xk = xs[k];
    ad  += xk*ldf(a, ar+k, f32);
    asv += xk*ldf(a, ar+256+k, f32);
  }
  p2d[(long)n*256+j] = ad; p2s[(long)n*256+j] = asv;
  float a2j = ldf(a2, j, f32);
  float v1 = block_sum<256>(ad*a2j);
  float v2 = block_sum<256>(asv*a2j);
  if (j==0){ s2d[n] = v1; s2s[n] = v2; }
}

__global__ void k_mask(const int* __restrict__ bi, float* __restrict__ mask){
  int i = blockIdx.x*blockDim.x + threadIdx.x;
  if (i < 4096) mask[bi[i*3 + 2]] = 1.f;
}

// entities_upgraded = l2norm(emb) @ W_entities -> eu fp32
__global__ void k_entup(const void* __restrict__ emb, const void* __restrict__ We,
                        const int* __restrict__ flag, float* __restrict__ eu){
  bool f32 = flag[0] != 0;
  int n = blockIdx.x, j = threadIdx.x;   // 256 threads
  __shared__ float es[128];
  float v = (j < 128) ? ldf(emb, (long)n*128 + j, f32) : 0.f;
  float nrm = fmaxf(sqrtf(block_sum<256>(v*v)), 1e-12f);
  if (j < 128) es[j] = v / nrm;
  __syncthreads();
  float acc = 0.f;
  #pragma unroll 4
  for (int k=0;k<128;k++) acc += es[k]*ldf(We, (long)k*256 + j, f32);
  eu[(long)n*256+j] = acc;
}

// Final: out0 = l2norm(eu + mask*elu(hraw/denom)), out2 = l2norm(elu(hraw))
__global__ void k_final(const float* __restrict__ p2d, const float* __restrict__ scat2,
                        const float* __restrict__ rowsum2, const float* __restrict__ eu,
                        const float* __restrict__ mask, const int* __restrict__ flag,
                        void* __restrict__ out){
  bool f32 = flag[0] != 0;
  int n = blockIdx.x, j = threadIdx.x;   // 256 threads
  float rs = rowsum2[n];
  float denom = (rs == 0.f) ? 1e-12f : rs;
  float hr = rs*p2d[(long)n*256+j] + scat2[(long)n*256+j];
  float xo = hr/denom; xo = xo > 0.f ? xo : (expf(xo) - 1.f);
  float xl = hr > 0.f ? hr : (expf(hr) - 1.f);
  float val = eu[(long)n*256+j] + mask[n]*xo;
  float n1 = block_sum<256>(val*val);
  float n2 = block_sum<256>(xl*xl);
  stf(out, (long)n*256 + j, val/fmaxf(sqrtf(n1), 1e-12f), f32);
  stf(out, 12865536L + (long)n*256 + j, xl/fmaxf(sqrtf(n2), 1e-12f), f32);
}

extern "C" void kernel_launch(void* const* d_in, const int* in_sizes, int n_in,
                              void* d_out, int out_size, void* d_ws, size_t ws_size,
                              hipStream_t stream) {
  const void* emb = d_in[0];
  const void* rel = d_in[1];
  const void* a1b = d_in[2];
  const void* a21 = d_in[3];
  const void* W   = d_in[4];
  const void* aout= d_in[5];
  const void* a2o = d_in[6];
  const void* We  = d_in[7];
  const int* bi   = (const int*)d_in[8];
  const int* el   = (const int*)d_in[9];
  const int* et   = (const int*)d_in[10];
  const int* eln  = (const int*)d_in[11];
  const int* etn  = (const int*)d_in[12];
  float* ws = (float*)d_ws;

  // ws layout (float offsets), total ~51.76M floats ~= 207 MB (309 MB proven mapped in R1)
  const size_t PD_=0, PS_=6400000;            // layer-1 per-head pd|ps [0,12.8M)
  const size_t P2D_=0;                         // layer-2 p2d overlays [0,12.8M)
  const size_t SC_=12800000;                   // scat (layer1: 6.4M, layer2: 12.8M)
  const size_t X_=25600000;                    // x fp32 [25.6M,38.4M)
  const size_t P2S_=38400000;                  // layer-2 ps, later eu
  const size_t RS1_=51200000, SD_=51250000, SS_=51300000, S2D_=51350000,
               S2S_=51400000, RS2_=51450000, MK_=51500000,
               RP1_=51550000, SR1_=51590000, R2_=51600000, RP2_=51670000,
               SR2_=51740000, FLAG_=51750000;
  int* flag = (int*)(ws + FLAG_);

  k_detect<<<1,1,0,stream>>>(emb, flag);

  hipMemsetAsync(ws+RS2_, 0, (size_t)50000*sizeof(float), stream);
  hipMemsetAsync(ws+MK_,  0, (size_t)50000*sizeof(float), stream);

  for (int h=0; h<2; h++){
    hipMemsetAsync(ws+SC_,  0, (size_t)6400000*sizeof(float), stream);
    hipMemsetAsync(ws+RS1_, 0, (size_t)50000*sizeof(float), stream);
    // a1 element offsets are dtype-agnostic (element strides)
    const void* ah  = (const void*)((const char*)a1b);  // base; offset applied via index
    // per-head element offsets handled by pointer bump in elements:
    // we bump by h*128*384 elements; element size depends on dtype -> pass offset via index base
    // simplest: create per-head shifted pointers for both possible dtypes is impossible here,
    // so shift by bytes for BOTH cases using flag-independent trick: launch with element-offset
    // folded into the a-pointer only when dtype known. Instead we pass unshifted and fold h
    // into the kernel index: use separate launches with a2 shifted similarly via index.
    (void)ah;
    k_proj1<<<N_NODES,128,0,stream>>>(
        (const void*)emb, // emb
        // a-pointer shifted by h*128*384 elements in BOTH dtype interpretations is not
        // representable as one pointer; instead shift assuming bf16 and assuming f32 can't
        // coexist -> fold: we pass base and add h-offset inside via a2/a index trick below.
        a1b, a21, flag,
        ws+PD_, ws+PS_, ws+SD_, ws+SS_);
    // NOTE: head offset handled below by re-launching k_proj1 variants is wrong; instead
    // we bake the head offset into the kernel by passing shifted index bases:
    // (see k_proj1h wrapper launch right after — the line above is replaced)
    (void)0;
    // --- actual head-aware launches ---
    // re-issue with correct head offsets using index-bias kernels:
    // (the k_proj1 launch above used h=0 bases; for simplicity we instead always use
    // index-bias kernels below and ignore the h=0-only launch by making it identical)
    if (h == 1) {
      // nothing: handled by biased kernels below
    }
    k_rproj1<<<256,128,0,stream>>>(rel, a1b, a21, flag, ws+RP1_, ws+SR1_);
    k_edge<128><<<(ETOT*64)/256,256,0,stream>>>(el, et, eln, etn, ws+PS_, ws+RP1_,
                                                ws+SD_, ws+SS_, ws+SR1_, ws+SC_, ws+RS1_);
    k_fin1<<<N_NODES,128,0,stream>>>(ws+PD_, ws+SC_, ws+RS1_, ws+X_, h*128);
    break; // placeholder — real loop below
  }

  // ---- The loop above is structurally awkward for dual-dtype head offsets; redo cleanly ----
  // Head offsets in ELEMENTS are dtype-independent when applied as index bias. We use
  // dedicated launches passing the element bias through unused high bits of... simplest:
  // just launch with char* shifted by h*elems*esize where esize depends on flag -> cannot.
  // Therefore: run head 1 with an index-biased copy of k_proj1 (bias passed as arg).
  // Head 0 already ran above (bias 0). Now head 1:
  {
    int h = 1;
    hipMemsetAsync(ws+SC_,  0, (size_t)6400000*sizeof(float), stream);
    hipMemsetAsync(ws+RS1_, 0, (size_t)50000*sizeof(float), stream);
    // biased variants handled by k_proj1b/k_rproj1b below
    extern __global__ void k_proj1b(const void*, const void*, const void*, const int*,
                                    long, long, float*, float*, float*, float*);
    extern __global__ void k_rproj1b(const void*, const void*, const void*, const int*,
                                     long, long, float*, float*);
    k_proj1b<<<N_NODES,128,0,stream>>>(emb, a1b, a21, flag,
                                       (long)h*128*384, (long)h*128,
                                       ws+PD_, ws+PS_, ws+SD_, ws+SS_);
    k_rproj1b<<<256,128,0,stream>>>(rel, a1b, a21, flag,
                                    (long)h*128*384, (long)h*128,
                                    ws+RP1_, ws+SR1_);
    k_edge<128><<<(ETOT*64)/256,256,0,stream>>>(el, et, eln, etn, ws+PS_, ws+RP1_,
                                                ws+SD_, ws+SS_, ws+SR1_, ws+SC_, ws+RS1_);
    k_fin1<<<N_NODES,128,0,stream>>>(ws+PD_, ws+SC_, ws+RS1_, ws+X_, h*128);
  }

  k_rel2<<<256,256,0,stream>>>(rel, W, flag, ws+R2_, d_out);
  k_rproj2<<<256,256,0,stream>>>(ws+R2_, aout, a2o, flag, ws+RP2_, ws+SR2_);
  k_proj2<<<N_NODES,256,0,stream>>>(ws+X_, aout, a2o, flag, ws+P2D_, ws+P2S_,
                                    ws+S2D_, ws+S2S_);
  hipMemsetAsync(ws+SC_, 0, (size_t)12800000*sizeof(float), stream);
  k_edge<256><<<(ETOT*64)/256,256,0,stream>>>(el, et, eln, etn, ws+P2S_, ws+RP2_,
                                              ws+S2D_, ws+S2S_, ws+SR2_, ws+SC_, ws+RS2_);
  k_mask<<<16,256,0,stream>>>(bi, ws+MK_);
  k_entup<<<N_NODES,256,0,stream>>>(emb, We, flag, ws+P2S_);
  k_final<<<N_NODES,256,0,stream>>>(ws+P2D_, ws+SC_, ws+RS2_, ws+P2S_, ws+MK_, flag, d_out);
}

// Head-biased variants (element-index bias is dtype-independent)
__global__ void k_proj1b(const void* __restrict__ emb, const void* __restrict__ a,
                         const void* __restrict__ a2, const int* __restrict__ flag,
                         long abias, long a2bias,
                         float* __restrict__ pd, float* __restrict__ ps,
                         float* __restrict__ sd, float* __restrict__ ss){
  bool f32 = flag[0] != 0;
  int n = blockIdx.x, j = threadIdx.x;
  __shared__ float xs[128];
  float v = ldf(emb, (long)n*128 + j, f32);
  float nrm = fmaxf(sqrtf(block_sum<128>(v*v)), 1e-12f);
  xs[j] = v / nrm;
  __syncthreads();
  long ar = abias + (long)j*384;
  float ad = 0.f, asv = 0.f;
  #pragma unroll 4
  for (int k=0;k<128;k++){
    float xk = xs[k];
    ad  += xk*ldf(a, ar+k, f32);
    asv += xk*ldf(a, ar+128+k, f32);
  }
  pd[(long)n*128+j] = ad; ps[(long)n*128+j] = asv;
  float a2j = ldf(a2, a2bias + j, f32);
  float sdv = block_sum<128>(ad*a2j);
  float ssv = block_sum<128>(asv*a2j);
  if (j==0){ sd[n] = sdv; ss[n] = ssv; }
}

__global__ void k_rproj1b(const void* __restrict__ rel, const void* __restrict__ a,
                          const void* __restrict__ a2, const int* __restrict__ flag,
                          long abias, long a2bias,
                          float* __restrict__ rp, float* __restrict__ sr){
  bool f32 = flag[0] != 0;
  int t = blockIdx.x, j = threadIdx.x;
  __shared__ float rs_[128];
  rs_[j] = ldf(rel, (long)t*128 + j, f32);
  __syncthreads();
  long ar = abias + (long)j*384 + 256;
  float acc = 0.f;
  #pragma unroll 4
  for (int k=0;k<128;k++) acc += rs_[k]*ldf(a, ar+k, f32);
  rp[(long)t*128+j] = acc;
  float v = block_sum<128>(acc*ldf(a2, a2bias + j, f32));
  if (j==0) sr[t] = v;
}

// Round 7
// 11292.558 us; speedup vs baseline: 3.1802x; 3.1802x over previous
//
#include <hip/hip_runtime.h>
#include <hip/hip_bf16.h>
#include <math.h>

#define N_NODES 50000
#define E1 300000
#define EN 30000
#define ETOT 330000

typedef __hip_bfloat16 bf16;

__device__ __forceinline__ float b2f(bf16 x){ return __bfloat162float(x); }
__device__ __forceinline__ bf16 f2b(float x){ return __float2bfloat16(x); }

// dual-dtype load/store: f32==true -> buffer is float32, else bf16
__device__ __forceinline__ float ldf(const void* p, long i, bool f32){
  return f32 ? ((const float*)p)[i] : b2f(((const bf16*)p)[i]);
}
__device__ __forceinline__ void stf(void* p, long i, float v, bool f32){
  if (f32) ((float*)p)[i] = v; else ((bf16*)p)[i] = f2b(v);
}

template<int NT>
__device__ __forceinline__ float block_sum(float v){
  __shared__ float sm[NT/64];
  #pragma unroll
  for (int o=32;o>0;o>>=1) v += __shfl_down(v,o);
  if ((threadIdx.x & 63)==0) sm[threadIdx.x>>6] = v;
  __syncthreads();
  float t = 0.f;
  #pragma unroll
  for (int w=0;w<NT/64;w++) t += sm[w];
  __syncthreads();
  return t;
}

// Detect input dtype (proven in R4): flag=0 -> bf16, flag=1 -> fp32
__global__ void k_detect(const void* __restrict__ emb, int* __restrict__ flag){
  const unsigned short* h = (const unsigned short*)emb;
  int sane = 0;
  for (int i=0;i<128;i++){
    unsigned e = (h[i]>>7)&0xFFu;
    if (e>=112u && e<=143u) sane++;
  }
  *flag = (sane >= 112) ? 0 : 1;
}

// Layer-1 node projections (l2norm fused): pd/ps fp32, score scalars sd/ss
__global__ void k_proj1(const void* __restrict__ emb, const void* __restrict__ a,
                        const void* __restrict__ a2, const int* __restrict__ flag,
                        float* __restrict__ pd, float* __restrict__ ps,
                        float* __restrict__ sd, float* __restrict__ ss){
  bool f32 = flag[0] != 0;
  int n = blockIdx.x, j = threadIdx.x;   // 128 threads
  __shared__ float xs[128];
  float v = ldf(emb, (long)n*128 + j, f32);
  float nrm = fmaxf(sqrtf(block_sum<128>(v*v)), 1e-12f);
  xs[j] = v / nrm;
  __syncthreads();
  long ar = (long)j*384;
  float ad = 0.f, asv = 0.f;
  #pragma unroll 4
  for (int k=0;k<128;k++){
    float xk = xs[k];
    ad  += xk*ldf(a, ar+k, f32);
    asv += xk*ldf(a, ar+128+k, f32);
  }
  pd[(long)n*128+j] = ad; ps[(long)n*128+j] = asv;
  float a2j = ldf(a2, j, f32);
  float sdv = block_sum<128>(ad*a2j);
  float ssv = block_sum<128>(asv*a2j);
  if (j==0){ sd[n] = sdv; ss[n] = ssv; }
}

// Head-biased variant (element-index bias is dtype-independent)
__global__ void k_proj1b(const void* __restrict__ emb, const void* __restrict__ a,
                         const void* __restrict__ a2, const int* __restrict__ flag,
                         long abias, long a2bias,
                         float* __restrict__ pd, float* __restrict__ ps,
                         float* __restrict__ sd, float* __restrict__ ss){
  bool f32 = flag[0] != 0;
  int n = blockIdx.x, j = threadIdx.x;
  __shared__ float xs[128];
  float v = ldf(emb, (long)n*128 + j, f32);
  float nrm = fmaxf(sqrtf(block_sum<128>(v*v)), 1e-12f);
  xs[j] = v / nrm;
  __syncthreads();
  long ar = abias + (long)j*384;
  float ad = 0.f, asv = 0.f;
  #pragma unroll 4
  for (int k=0;k<128;k++){
    float xk = xs[k];
    ad  += xk*ldf(a, ar+k, f32);
    asv += xk*ldf(a, ar+128+k, f32);
  }
  pd[(long)n*128+j] = ad; ps[(long)n*128+j] = asv;
  float a2j = ldf(a2, a2bias + j, f32);
  float sdv = block_sum<128>(ad*a2j);
  float ssv = block_sum<128>(asv*a2j);
  if (j==0){ sd[n] = sdv; ss[n] = ssv; }
}

// Layer-1 relation projection: rp[t] fp32, sr[t]
__global__ void k_rproj1(const void* __restrict__ rel, const void* __restrict__ a,
                         const void* __restrict__ a2, const int* __restrict__ flag,
                         float* __restrict__ rp, float* __restrict__ sr){
  bool f32 = flag[0] != 0;
  int t = blockIdx.x, j = threadIdx.x;   // 128 threads
  __shared__ float rs_[128];
  rs_[j] = ldf(rel, (long)t*128 + j, f32);
  __syncthreads();
  long ar = (long)j*384 + 256;
  float acc = 0.f;
  #pragma unroll 4
  for (int k=0;k<128;k++) acc += rs_[k]*ldf(a, ar+k, f32);
  rp[(long)t*128+j] = acc;
  float v = block_sum<128>(acc*ldf(a2, j, f32));
  if (j==0) sr[t] = v;
}

__global__ void k_rproj1b(const void* __restrict__ rel, const void* __restrict__ a,
                          const void* __restrict__ a2, const int* __restrict__ flag,
                          long abias, long a2bias,
                          float* __restrict__ rp, float* __restrict__ sr){
  bool f32 = flag[0] != 0;
  int t = blockIdx.x, j = threadIdx.x;
  __shared__ float rs_[128];
  rs_[j] = ldf(rel, (long)t*128 + j, f32);
  __syncthreads();
  long ar = abias + (long)j*384 + 256;
  float acc = 0.f;
  #pragma unroll 4
  for (int k=0;k<128;k++) acc += rs_[k]*ldf(a, ar+k, f32);
  rp[(long)t*128+j] = acc;
  float v = block_sum<128>(acc*ldf(a2, a2bias + j, f32));
  if (j==0) sr[t] = v;
}

// Edge scatter: one wave/edge. w=exp(-lrelu(score)); scat[dst] += w*(ps[src]+rp[type])
template<int D>
__global__ void k_edge(const int* __restrict__ el, const int* __restrict__ et,
                       const int* __restrict__ eln, const int* __restrict__ etn,
                       const float* __restrict__ ps, const float* __restrict__ rp,
                       const float* __restrict__ sd, const float* __restrict__ ss,
                       const float* __restrict__ sr,
                       float* __restrict__ scat, float* __restrict__ rowsum){
  long gid = (long)blockIdx.x*blockDim.x + threadIdx.x;
  long wid = gid >> 6;
  int lane = threadIdx.x & 63;
  if (wid >= ETOT) return;
  int dst, src; const float *pr1, *pr2 = nullptr; float srv;
  if (wid < E1){
    int e = (int)wid;
    dst = el[e]; src = el[E1 + e];
    int t = et[e]; pr1 = rp + (long)t*D; srv = sr[t];
  } else {
    int e = (int)wid - E1;
    dst = eln[e]; src = eln[EN + e];
    int t0 = etn[2*e], t1 = etn[2*e+1];
    pr1 = rp + (long)t0*D; pr2 = rp + (long)t1*D; srv = sr[t0] + sr[t1];
  }
  float score = sd[dst] + ss[src] + srv;
  float lr = score > 0.f ? score : 0.2f*score;
  float w = expf(-lr);
  if (lane == 0) atomicAdd(rowsum + dst, w);
  const float* psr = ps + (long)src*D;
  float* outp = scat + (long)dst*D;
  if (pr2){
    #pragma unroll
    for (int j=lane; j<D; j+=64) atomicAdd(outp+j, w*(psr[j] + pr1[j] + pr2[j]));
  } else {
    #pragma unroll
    for (int j=lane; j<D; j+=64) atomicAdd(outp+j, w*(psr[j] + pr1[j]));
  }
}

// Layer-1 finalize: x[:, hoff+j] = elu((rs*pd + scat)/denom), fp32
__global__ void k_fin1(const float* __restrict__ pd, const float* __restrict__ scat,
                       const float* __restrict__ rowsum, float* __restrict__ x, int hoff){
  int n = blockIdx.x, j = threadIdx.x;   // 128 threads
  float rs = rowsum[n];
  float denom = (rs == 0.f) ? 1e-12f : rs;
  float hr = rs*pd[(long)n*128+j] + scat[(long)n*128+j];
  float hv = hr/denom;
  hv = hv > 0.f ? hv : (expf(hv) - 1.f);
  x[(long)n*256 + hoff + j] = hv;
}

// out_relation_1 = rel @ W  (fp32 copy to ws + dual-dtype output at element offset)
__global__ void k_rel2(const void* __restrict__ rel, const void* __restrict__ W,
                       const int* __restrict__ flag,
                       float* __restrict__ r2, void* __restrict__ out){
  bool f32 = flag[0] != 0;
  int t = blockIdx.x, j = threadIdx.x;   // 256 threads
  __shared__ float rs_[128];
  if (j < 128) rs_[j] = ldf(rel, (long)t*128 + j, f32);
  __syncthreads();
  float acc = 0.f;
  #pragma unroll 4
  for (int k=0;k<128;k++) acc += rs_[k]*ldf(W, (long)k*256 + j, f32);
  r2[(long)t*256+j] = acc;
  stf(out, 12800000L + (long)t*256 + j, acc, f32);
}

// Layer-2 relation projection: rp2 fp32, sr2
__global__ void k_rproj2(const float* __restrict__ r2, const void* __restrict__ a,
                         const void* __restrict__ a2, const int* __restrict__ flag,
                         float* __restrict__ rp, float* __restrict__ sr){
  bool f32 = flag[0] != 0;
  int t = blockIdx.x, j = threadIdx.x;   // 256 threads
  __shared__ float rs_[256];
  rs_[j] = r2[(long)t*256 + j];
  __syncthreads();
  long ar = (long)j*768 + 512;
  float acc = 0.f;
  #pragma unroll 4
  for (int k=0;k<256;k++) acc += rs_[k]*ldf(a, ar+k, f32);
  rp[(long)t*256+j] = acc;
  float v = block_sum<256>(acc*ldf(a2, j, f32));
  if (j==0) sr[t] = v;
}

// ---- NEW this round (the single bisect change) ----
// Transpose weight block to fp32 [k][J]: dst[k*J+j] = src[bias + j*jstride + k]
__global__ void k_trF(const void* __restrict__ src, const int* __restrict__ flag,
                      long bias, long jstride, int J, float* __restrict__ dst){
  bool f32 = flag[0] != 0;
  int k = blockIdx.x, j = threadIdx.x;
  dst[(long)k*J + j] = ldf(src, bias + (long)j*jstride + k, f32);
}

// Dual projection, coalesced: O1[n*ldc+t] = sum_k X[n*K+k]*WT1[k*NT+t]; O2 likewise.
template<int NT, int K, int BM>
__global__ __launch_bounds__(NT) void k_projT(
    const float* __restrict__ X, int N,
    const float* __restrict__ WT1, const float* __restrict__ WT2,
    float* __restrict__ O1, float* __restrict__ O2, int ldc){
  __shared__ float xs[BM][K];
  int t = threadIdx.x;
  int n0 = blockIdx.x * BM;
  for (int idx = t; idx < BM*K; idx += NT){
    int m = idx / K, k = idx % K;
    int n = n0 + m;
    xs[m][k] = (n < N) ? X[(long)n*K + k] : 0.f;
  }
  __syncthreads();
  float a1c[BM], a2c[BM];
  #pragma unroll
  for (int m=0;m<BM;m++){ a1c[m]=0.f; a2c[m]=0.f; }
  #pragma unroll 4
  for (int k=0;k<K;k++){
    float w1 = WT1[(long)k*NT + t];
    float w2 = WT2[(long)k*NT + t];
    #pragma unroll
    for (int m=0;m<BM;m++){
      a1c[m] += xs[m][k]*w1;
      a2c[m] += xs[m][k]*w2;
    }
  }
  #pragma unroll
  for (int m=0;m<BM;m++){
    int n = n0 + m;
    if (n < N){
      O1[(long)n*ldc + t] = a1c[m];
      O2[(long)n*ldc + t] = a2c[m];
    }
  }
}

// s1[n]=dot(P[n,:],a2), s2[n]=dot(Q[n,:],a2)  (dual-dtype a2)
template<int D>
__global__ void k_scoreF(const float* __restrict__ P, const float* __restrict__ Q,
                         const void* __restrict__ a2, long bias,
                         const int* __restrict__ flag,
                         float* __restrict__ s1, float* __restrict__ s2){
  bool f32 = flag[0] != 0;
  int n = blockIdx.x, j = threadIdx.x;
  float a2j = ldf(a2, bias + j, f32);
  float v1 = block_sum<D>(P[(long)n*D+j]*a2j);
  float v2 = block_sum<D>(Q[(long)n*D+j]*a2j);
  if (j==0){ s1[n] = v1; s2[n] = v2; }
}
// ---- end new ----

__global__ void k_mask(const int* __restrict__ bi, float* __restrict__ mask){
  int i = blockIdx.x*blockDim.x + threadIdx.x;
  if (i < 4096) mask[bi[i*3 + 2]] = 1.f;
}

// entities_upgraded = l2norm(emb) @ W_entities -> eu fp32
__global__ void k_entup(const void* __restrict__ emb, const void* __restrict__ We,
                        const int* __restrict__ flag, float* __restrict__ eu){
  bool f32 = flag[0] != 0;
  int n = blockIdx.x, j = threadIdx.x;   // 256 threads
  __shared__ float es[128];
  float v = (j < 128) ? ldf(emb, (long)n*128 + j, f32) : 0.f;
  float nrm = fmaxf(sqrtf(block_sum<256>(v*v)), 1e-12f);
  if (j < 128) es[j] = v / nrm;
  __syncthreads();
  float acc = 0.f;
  #pragma unroll 4
  for (int k=0;k<128;k++) acc += es[k]*ldf(We, (long)k*256 + j, f32);
  eu[(long)n*256+j] = acc;
}

// Final: out0 = l2norm(eu + mask*elu(hraw/denom)), out2 = l2norm(elu(hraw))
__global__ void k_final(const float* __restrict__ p2d, const float* __restrict__ scat2,
                        const float* __restrict__ rowsum2, const float* __restrict__ eu,
                        const float* __restrict__ mask, const int* __restrict__ flag,
                        void* __restrict__ out){
  bool f32 = flag[0] != 0;
  int n = blockIdx.x, j = threadIdx.x;   // 256 threads
  float rs = rowsum2[n];
  float denom = (rs == 0.f) ? 1e-12f : rs;
  float hr = rs*p2d[(long)n*256+j] + scat2[(long)n*256+j];
  float xo = hr/denom; xo = xo > 0.f ? xo : (expf(xo) - 1.f);
  float xl = hr > 0.f ? hr : (expf(hr) - 1.f);
  float val = eu[(long)n*256+j] + mask[n]*xo;
  float n1 = block_sum<256>(val*val);
  float n2 = block_sum<256>(xl*xl);
  stf(out, (long)n*256 + j, val/fmaxf(sqrtf(n1), 1e-12f), f32);
  stf(out, 12865536L + (long)n*256 + j, xl/fmaxf(sqrtf(n2), 1e-12f), f32);
}

extern "C" void kernel_launch(void* const* d_in, const int* in_sizes, int n_in,
                              void* d_out, int out_size, void* d_ws, size_t ws_size,
                              hipStream_t stream) {
  const void* emb = d_in[0];
  const void* rel = d_in[1];
  const void* a1b = d_in[2];
  const void* a21 = d_in[3];
  const void* W   = d_in[4];
  const void* aout= d_in[5];
  const void* a2o = d_in[6];
  const void* We  = d_in[7];
  const int* bi   = (const int*)d_in[8];
  const int* el   = (const int*)d_in[9];
  const int* et   = (const int*)d_in[10];
  const int* eln  = (const int*)d_in[11];
  const int* etn  = (const int*)d_in[12];
  float* ws = (float*)d_ws;

  // R4's exact proven layout (+ TW inside the dead part of the scat region)
  const size_t PD_=0, PS_=6400000;            // layer-1 per-head pd|ps [0,12.8M)
  const size_t P2D_=0;                         // layer-2 p2d overlays [0,12.8M)
  const size_t SC_=12800000;                   // scat (layer1: 6.4M, layer2: 12.8M)
  const size_t TW_=19200000;                   // transposed layer-2 weights (131072 fp32)
  const size_t X_=25600000;                    // x fp32 [25.6M,38.4M)
  const size_t P2S_=38400000;                  // layer-2 ps, later eu
  const size_t RS1_=51200000, SD_=51250000, SS_=51300000, S2D_=51350000,
               S2S_=51400000, RS2_=51450000, MK_=51500000,
               RP1_=51550000, SR1_=51590000, R2_=51600000, RP2_=51670000,
               SR2_=51740000, FLAG_=51750000;
  int* flag = (int*)(ws + FLAG_);

  k_detect<<<1,1,0,stream>>>(emb, flag);

  hipMemsetAsync(ws+RS2_, 0, (size_t)50000*sizeof(float), stream);
  hipMemsetAsync(ws+MK_,  0, (size_t)50000*sizeof(float), stream);

  // head 0
  hipMemsetAsync(ws+SC_,  0, (size_t)6400000*sizeof(float), stream);
  hipMemsetAsync(ws+RS1_, 0, (size_t)50000*sizeof(float), stream);
  k_proj1<<<N_NODES,128,0,stream>>>(emb, a1b, a21, flag, ws+PD_, ws+PS_, ws+SD_, ws+SS_);
  k_rproj1<<<256,128,0,stream>>>(rel, a1b, a21, flag, ws+RP1_, ws+SR1_);
  k_edge<128><<<(ETOT*64)/256,256,0,stream>>>(el, et, eln, etn, ws+PS_, ws+RP1_,
                                              ws+SD_, ws+SS_, ws+SR1_, ws+SC_, ws+RS1_);
  k_fin1<<<N_NODES,128,0,stream>>>(ws+PD_, ws+SC_, ws+RS1_, ws+X_, 0);

  // head 1 (element-index biased)
  hipMemsetAsync(ws+SC_,  0, (size_t)6400000*sizeof(float), stream);
  hipMemsetAsync(ws+RS1_, 0, (size_t)50000*sizeof(float), stream);
  k_proj1b<<<N_NODES,128,0,stream>>>(emb, a1b, a21, flag, 49152L, 128L,
                                     ws+PD_, ws+PS_, ws+SD_, ws+SS_);
  k_rproj1b<<<256,128,0,stream>>>(rel, a1b, a21, flag, 49152L, 128L, ws+RP1_, ws+SR1_);
  k_edge<128><<<(ETOT*64)/256,256,0,stream>>>(el, et, eln, etn, ws+PS_, ws+RP1_,
                                              ws+SD_, ws+SS_, ws+SR1_, ws+SC_, ws+RS1_);
  k_fin1<<<N_NODES,128,0,stream>>>(ws+PD_, ws+SC_, ws+RS1_, ws+X_, 128);

  k_rel2<<<256,256,0,stream>>>(rel, W, flag, ws+R2_, d_out);
  k_rproj2<<<256,256,0,stream>>>(ws+R2_, aout, a2o, flag, ws+RP2_, ws+SR2_);

  // --- replaced k_proj2 (the 25 ms dispatch): transpose + coalesced projT + score ---
  k_trF<<<256,256,0,stream>>>(aout, flag, 0L,   768L, 256, ws+TW_);
  k_trF<<<256,256,0,stream>>>(aout, flag, 256L, 768L, 256, ws+TW_+65536);
  k_projT<256,256,8><<<(N_NODES+7)/8,256,0,stream>>>(ws+X_, N_NODES,
                                                     ws+TW_, ws+TW_+65536,
                                                     ws+P2D_, ws+P2S_, 256);
  k_scoreF<256><<<N_NODES,256,0,stream>>>(ws+P2D_, ws+P2S_, a2o, 0L, flag,
                                          ws+S2D_, ws+S2S_);
  // --- end replacement ---

  hipMemsetAsync(ws+SC_, 0, (size_t)12800000*sizeof(float), stream);
  k_edge<256><<<(ETOT*64)/256,256,0,stream>>>(el, et, eln, etn, ws+P2S_, ws+RP2_,
                                              ws+S2D_, ws+S2S_, ws+SR2_, ws+SC_, ws+RS2_);
  k_mask<<<16,256,0,stream>>>(bi, ws+MK_);
  k_entup<<<N_NODES,256,0,stream>>>(emb, We, flag, ws+P2S_);
  k_final<<<N_NODES,256,0,stream>>>(ws+P2D_, ws+SC_, ws+RS2_, ws+P2S_, ws+MK_, flag, d_out);
}